// Round 3
// baseline (524.457 us; speedup 1.0000x reference)
//
#include <hip/hip_runtime.h>
#include <stdint.h>

#define N_NODES 8192
#define CH 256
#define MT 32
#define BK 64
#define KB_COUNT (N_NODES / BK)  // 128
#define ZROWS 16

typedef __bf16 bf16x8 __attribute__((ext_vector_type(8)));
typedef float f32x4 __attribute__((ext_vector_type(4)));
typedef unsigned int u32x4 __attribute__((ext_vector_type(4)));

// ---- async global->LDS, 16B per lane. LDS dest is the WAVE-UNIFORM base;
// HW scatters lane l to base + 16*l.
__device__ __forceinline__ void async_copy16(const void* g, void* l) {
  __builtin_amdgcn_global_load_lds(
      (const __attribute__((address_space(1))) void*)(uintptr_t)g,
      (__attribute__((address_space(3))) void*)(uint32_t)(uintptr_t)l,
      16, 0, 0);
}

__device__ __forceinline__ unsigned short f32_to_bf16_rne(float f) {
  unsigned u = __float_as_uint(f);
  u += 0x7FFFu + ((u >> 16) & 1u);
  return (unsigned short)(u >> 16);
}

// ---------------- K1: dsq = rsqrt(rowsum(adj) + 1), wave-per-row ----------------
__global__ void __launch_bounds__(256) k_deg(const float* __restrict__ adj,
                                             float* __restrict__ dsq) {
  const int wave = threadIdx.x >> 6, lane = threadIdx.x & 63;
  const int row = blockIdx.x * 4 + wave;
  const f32x4* ar = (const f32x4*)(adj + (size_t)row * N_NODES);
  float s0 = 0.f, s1 = 0.f, s2 = 0.f, s3 = 0.f;
#pragma unroll
  for (int i = 0; i < 8; ++i) {
    f32x4 a = ar[lane + 64 * (4 * i + 0)];
    f32x4 b = ar[lane + 64 * (4 * i + 1)];
    f32x4 c = ar[lane + 64 * (4 * i + 2)];
    f32x4 d = ar[lane + 64 * (4 * i + 3)];
    s0 += (a.x + a.y) + (a.z + a.w);
    s1 += (b.x + b.y) + (b.z + b.w);
    s2 += (c.x + c.y) + (c.z + c.w);
    s3 += (d.x + d.y) + (d.z + d.w);
  }
  float s = (s0 + s1) + (s2 + s3);
#pragma unroll
  for (int off = 32; off > 0; off >>= 1) s += __shfl_down(s, off, 64);
  if (lane == 0) dsq[row] = rsqrtf(s + 1.0f);
}

// -------- K2: z = x @ w (fp32); yt[c][j] = bf16(dsq[j] * z[j][c]) (transposed) ------
__global__ void __launch_bounds__(256) k_zy(const float* __restrict__ x,
                                            const float* __restrict__ w,
                                            const float* __restrict__ dsq,
                                            float* __restrict__ z,
                                            unsigned short* __restrict__ yt) {
  __shared__ float xs[ZROWS][CH];
  const int r0 = blockIdx.x * ZROWS;
  const int t = threadIdx.x;
#pragma unroll
  for (int r = 0; r < ZROWS; ++r) xs[r][t] = x[(size_t)(r0 + r) * CH + t];
  __syncthreads();
  float acc[ZROWS];
#pragma unroll
  for (int r = 0; r < ZROWS; ++r) acc[r] = 0.f;
  for (int k = 0; k < CH; k += 8) {
    float wv[8];
#pragma unroll
    for (int u = 0; u < 8; ++u) wv[u] = w[(size_t)(k + u) * CH + t];
#pragma unroll
    for (int r = 0; r < ZROWS; ++r) {
#pragma unroll
      for (int u = 0; u < 8; ++u) acc[r] += xs[r][k + u] * wv[u];
    }
  }
#pragma unroll
  for (int r = 0; r < ZROWS; ++r) z[(size_t)(r0 + r) * CH + t] = acc[r];
#pragma unroll
  for (int r = 0; r < ZROWS; ++r)
    yt[(size_t)t * N_NODES + r0 + r] = f32_to_bf16_rne(dsq[r0 + r] * acc[r]);
}

// -------- K3: S = adj @ y ; out = elu(dsq_i*(S + dsq_i*z_i)) -> d_out ----------
// Tile: 32 rows x 256 cols, full K. 4 waves split N (64 cols each).
// LDS (double buffered): A fp32 [32][64] (8KB), B bf16 [256][64] (32KB), XOR-swizzled
// at 16B-chunk granularity so frag ds_read_b128 is <=2-way bank conflict (free).
//
// Pipeline (single barrier per K-iter, compiler-managed waits):
//   issue(buf0); loop { __syncthreads(); issue(other); compute(this); }
// At each __syncthreads() the only outstanding VMEM ops are this tile's 10 DMAs,
// so the compiler's vmcnt(0) drain waits exactly for them; the prefetch issued
// after the barrier overlaps the whole compute phase. No hand-rolled vmcnt.
__global__ void __launch_bounds__(256, 1) k_gemm1(const float* __restrict__ adj,
                                                  const unsigned short* __restrict__ yt,
                                                  const float* __restrict__ z,
                                                  const float* __restrict__ dsq,
                                                  float* __restrict__ out) {
  __shared__ __align__(16) float As[2][MT * BK];           // 8 KB each
  __shared__ __align__(16) unsigned short Bs[2][CH * BK];  // 32 KB each

  const int tid = threadIdx.x;
  const int wave = tid >> 6;
  const int lane = tid & 63;
  const int m0 = blockIdx.x * MT;
  const int lr = lane & 15;  // row/col within 16
  const int lq = lane >> 4;  // quad 0..3

  // A staging: 8 wave-instrs total, 2 per wave. instr i covers chunks s=64i+l.
  // chunk s -> (row = s>>4, swizzled c16 = (s&15)); global c16 = (l&15)^(row&15).
  const float* ag[2];
  int aoffu[2];
#pragma unroll
  for (int q = 0; q < 2; ++q) {
    int i = wave * 2 + q;
    int s = 64 * i + lane;
    int row = s >> 4;
    int c16 = (lane & 15) ^ (row & 15);
    ag[q] = adj + (size_t)(m0 + row) * N_NODES + c16 * 4;
    aoffu[q] = 64 * i * 16;
  }
  // B staging: 32 wave-instrs, 8 per wave. chunk s -> (n = s>>3, x=s&7); c8=(l&7)^(n&7).
  // Wave w stages exactly the n-range [64w, 64w+64) it later reads.
  const unsigned short* bg[8];
  int boffu[8];
#pragma unroll
  for (int q = 0; q < 8; ++q) {
    int i = wave * 8 + q;
    int s = 64 * i + lane;
    int n = s >> 3;
    int c8 = (lane & 7) ^ (n & 7);
    bg[q] = yt + (size_t)n * N_NODES + c8 * 8;
    boffu[q] = 64 * i * 16;
  }

  f32x4 acc[2][4];
#pragma unroll
  for (int i = 0; i < 2; ++i)
#pragma unroll
    for (int j = 0; j < 4; ++j) acc[i][j] = (f32x4){0.f, 0.f, 0.f, 0.f};

  auto issue = [&](int b, int k0) {
    char* aL = (char*)&As[b][0];
    char* bL = (char*)&Bs[b][0];
#pragma unroll
    for (int q = 0; q < 2; ++q) async_copy16(ag[q] + k0, aL + aoffu[q]);
#pragma unroll
    for (int q = 0; q < 8; ++q) async_copy16(bg[q] + k0, bL + boffu[q]);
  };

  issue(0, 0);

  for (int kb = 0; kb < KB_COUNT; ++kb) {
    const int b = kb & 1;
    // Drains this tile's DMAs (vmcnt(0)) and last iter's LDS reads (lgkmcnt(0)),
    // then rendezvous: tile b is ready for all waves, buffer b^1 is free.
    __syncthreads();
    if (kb + 1 < KB_COUNT) issue(b ^ 1, (kb + 1) * BK);

    const char* aB = (const char*)&As[b][0];
    const char* bB = (const char*)&Bs[b][0];

#pragma unroll
    for (int k32 = 0; k32 < 2; ++k32) {
      bf16x8 afr[2];
#pragma unroll
      for (int mt = 0; mt < 2; ++mt) {
        int row = mt * 16 + lr;
        int c16 = k32 * 8 + lq * 2;
        int s0 = row * 16 + ((c16) ^ (row & 15));
        int s1 = row * 16 + ((c16 + 1) ^ (row & 15));
        f32x4 r0 = *(const f32x4*)(aB + s0 * 16);
        f32x4 r1 = *(const f32x4*)(aB + s1 * 16);
        u32x4 pk;
        pk.x = __builtin_amdgcn_perm(__float_as_uint(r0.y), __float_as_uint(r0.x), 0x07060302u);
        pk.y = __builtin_amdgcn_perm(__float_as_uint(r0.w), __float_as_uint(r0.z), 0x07060302u);
        pk.z = __builtin_amdgcn_perm(__float_as_uint(r1.y), __float_as_uint(r1.x), 0x07060302u);
        pk.w = __builtin_amdgcn_perm(__float_as_uint(r1.w), __float_as_uint(r1.z), 0x07060302u);
        afr[mt] = __builtin_bit_cast(bf16x8, pk);
      }
#pragma unroll
      for (int nt = 0; nt < 4; ++nt) {
        int n = wave * 64 + nt * 16 + lr;
        int c8 = k32 * 4 + lq;
        int s = n * 8 + (c8 ^ (n & 7));
        bf16x8 bfr = *(const bf16x8*)(bB + s * 16);
        acc[0][nt] = __builtin_amdgcn_mfma_f32_16x16x32_bf16(afr[0], bfr, acc[0][nt], 0, 0, 0);
        acc[1][nt] = __builtin_amdgcn_mfma_f32_16x16x32_bf16(afr[1], bfr, acc[1][nt], 0, 0, 0);
      }
    }
  }

  // epilogue: out[i][c] = elu(dsq_i * (acc + dsq_i * z[i][c]))
#pragma unroll
  for (int mt = 0; mt < 2; ++mt) {
#pragma unroll
    for (int r = 0; r < 4; ++r) {
      int row = m0 + mt * 16 + lq * 4 + r;
      float di = dsq[row];
#pragma unroll
      for (int nt = 0; nt < 4; ++nt) {
        int col = wave * 64 + nt * 16 + lr;
        float v = acc[mt][nt][r];
        v = di * (v + di * z[(size_t)row * CH + col]);
        v = v > 0.f ? v : expm1f(v);
        out[(size_t)row * CH + col] = v;
      }
    }
  }
}

extern "C" void kernel_launch(void* const* d_in, const int* in_sizes, int n_in,
                              void* d_out, int out_size, void* d_ws, size_t ws_size,
                              hipStream_t stream) {
  const float* x = (const float*)d_in[0];
  const float* adj = (const float*)d_in[1];
  const float* w = (const float*)d_in[2];
  float* out = (float*)d_out;

  // ws layout: dsq [8192 f32] @0 ; yt [256][8192] bf16 @32KB ; z [8192][256] f32 after
  float* dsq = (float*)d_ws;
  unsigned short* yt = (unsigned short*)((char*)d_ws + 32768);
  float* z = (float*)((char*)d_ws + 32768 + (size_t)CH * N_NODES * 2);

  k_deg<<<N_NODES / 4, 256, 0, stream>>>(adj, dsq);
  k_zy<<<N_NODES / ZROWS, 256, 0, stream>>>(x, w, dsq, z, yt);
  k_gemm1<<<N_NODES / MT, 256, 0, stream>>>(adj, yt, z, dsq, out);
}

// Round 4
// 506.129 us; speedup vs baseline: 1.0362x; 1.0362x over previous
//
#include <hip/hip_runtime.h>
#include <stdint.h>

#define N_NODES 8192
#define CH 256
#define MT 32
#define BK 64
#define KB_COUNT 128
#define ZROWS 16
#define ZBLOCKS (N_NODES / ZROWS)  // 512
#define DEGBLOCKS (N_NODES / 4)    // 2048

typedef __bf16 bf16x8 __attribute__((ext_vector_type(8)));
typedef float f32x4 __attribute__((ext_vector_type(4)));
typedef unsigned short u16x4 __attribute__((ext_vector_type(4)));

// ---- async global->LDS, 16B per lane. LDS dest is the WAVE-UNIFORM base;
// HW scatters lane l to base + 16*l.
__device__ __forceinline__ void async_copy16(const void* g, void* l) {
  __builtin_amdgcn_global_load_lds(
      (const __attribute__((address_space(1))) void*)(uintptr_t)g,
      (__attribute__((address_space(3))) void*)(uint32_t)(uintptr_t)l,
      16, 0, 0);
}

__device__ __forceinline__ unsigned short f32_to_bf16_rne(float f) {
  unsigned u = __float_as_uint(f);
  u += 0x7FFFu + ((u >> 16) & 1u);
  return (unsigned short)(u >> 16);
}

__device__ __forceinline__ u16x4 f32x4_to_bf16_rne(f32x4 v) {
  u16x4 r;
  r.x = f32_to_bf16_rne(v.x);
  r.y = f32_to_bf16_rne(v.y);
  r.z = f32_to_bf16_rne(v.z);
  r.w = f32_to_bf16_rne(v.w);
  return r;
}

// ---- Pass 1 (heterogeneous blocks):
//   blocks [0, ZBLOCKS):           z = x @ w  (fp32, 16 rows/block)
//   blocks [ZBLOCKS, ZBLOCKS+2048): deg rowsums (4 rows/block, wave-per-row)
//                                   + write adj as bf16 (RNE) to adjb
// z-blocks first so their compute overlaps the deg blocks' HBM stream.
__global__ void __launch_bounds__(256) k_pass1(const float* __restrict__ x,
                                               const float* __restrict__ w,
                                               const float* __restrict__ adj,
                                               float* __restrict__ z,
                                               float* __restrict__ dsq,
                                               unsigned short* __restrict__ adjb) {
  __shared__ float xs[ZROWS][CH];
  if (blockIdx.x < ZBLOCKS) {
    const int r0 = blockIdx.x * ZROWS;
    const int t = threadIdx.x;
#pragma unroll
    for (int r = 0; r < ZROWS; ++r) xs[r][t] = x[(size_t)(r0 + r) * CH + t];
    __syncthreads();
    float acc[ZROWS];
#pragma unroll
    for (int r = 0; r < ZROWS; ++r) acc[r] = 0.f;
    for (int k = 0; k < CH; k += 8) {
      float wv[8];
#pragma unroll
      for (int u = 0; u < 8; ++u) wv[u] = w[(size_t)(k + u) * CH + t];
#pragma unroll
      for (int r = 0; r < ZROWS; ++r) {
#pragma unroll
        for (int u = 0; u < 8; ++u) acc[r] += xs[r][k + u] * wv[u];
      }
    }
#pragma unroll
    for (int r = 0; r < ZROWS; ++r) z[(size_t)(r0 + r) * CH + t] = acc[r];
  } else {
    const int wave = threadIdx.x >> 6, lane = threadIdx.x & 63;
    const int row = (blockIdx.x - ZBLOCKS) * 4 + wave;
    const f32x4* ar = (const f32x4*)(adj + (size_t)row * N_NODES);
    u16x4* br = (u16x4*)(adjb + (size_t)row * N_NODES);
    float s0 = 0.f, s1 = 0.f, s2 = 0.f, s3 = 0.f;
#pragma unroll
    for (int i = 0; i < 8; ++i) {
      f32x4 a = ar[lane + 64 * (4 * i + 0)];
      f32x4 b = ar[lane + 64 * (4 * i + 1)];
      f32x4 c = ar[lane + 64 * (4 * i + 2)];
      f32x4 d = ar[lane + 64 * (4 * i + 3)];
      br[lane + 64 * (4 * i + 0)] = f32x4_to_bf16_rne(a);
      br[lane + 64 * (4 * i + 1)] = f32x4_to_bf16_rne(b);
      br[lane + 64 * (4 * i + 2)] = f32x4_to_bf16_rne(c);
      br[lane + 64 * (4 * i + 3)] = f32x4_to_bf16_rne(d);
      s0 += (a.x + a.y) + (a.z + a.w);
      s1 += (b.x + b.y) + (b.z + b.w);
      s2 += (c.x + c.y) + (c.z + c.w);
      s3 += (d.x + d.y) + (d.z + d.w);
    }
    float s = (s0 + s1) + (s2 + s3);
#pragma unroll
    for (int off = 32; off > 0; off >>= 1) s += __shfl_down(s, off, 64);
    if (lane == 0) dsq[row] = rsqrtf(s + 1.0f);
  }
}

// ---- Pass 2: yt[c][j] = bf16(dsq[j] * z[j][c])  (transposed, k-contiguous)
__global__ void __launch_bounds__(256) k_y(const float* __restrict__ z,
                                           const float* __restrict__ dsq,
                                           unsigned short* __restrict__ yt) {
  const int r0 = blockIdx.x * 16;
  const int t = threadIdx.x;
  unsigned short vals[16];
#pragma unroll
  for (int r = 0; r < 16; ++r)
    vals[r] = f32_to_bf16_rne(dsq[r0 + r] * z[(size_t)(r0 + r) * CH + t]);
  // 16 consecutive bf16 per lane -> two 16B stores
  *(u16x4*)&yt[(size_t)t * N_NODES + r0 + 0] = *(u16x4*)&vals[0];
  *(u16x4*)&yt[(size_t)t * N_NODES + r0 + 4] = *(u16x4*)&vals[4];
  *(u16x4*)&yt[(size_t)t * N_NODES + r0 + 8] = *(u16x4*)&vals[8];
  *(u16x4*)&yt[(size_t)t * N_NODES + r0 + 12] = *(u16x4*)&vals[12];
}

// ---- Pass 3: S = adjb @ y ; out = elu(dsq_i*(S + dsq_i*z_i))
// 512 threads / 8 waves (2 per SIMD), each wave owns 32 cols. MT=32 rows, full K.
// A bf16 [32][64] (4KB x2), B bf16 [256][64] (32KB x2); both XOR-swizzled at
// 16B-chunk granularity: LDS chunk p = r*8 + (c8 ^ (r&7)) -> <=2-way conflicts (free).
// Single barrier per K-iter: __syncthreads drains this tile's DMAs (vmcnt(0)),
// then prefetch of the next tile is issued and overlaps the whole compute phase.
__global__ void __launch_bounds__(512, 1) k_gemm1(const unsigned short* __restrict__ adjb,
                                                  const unsigned short* __restrict__ yt,
                                                  const float* __restrict__ z,
                                                  const float* __restrict__ dsq,
                                                  float* __restrict__ out) {
  __shared__ __align__(16) unsigned short As[2][MT * BK];  // 4 KB each
  __shared__ __align__(16) unsigned short Bs[2][CH * BK];  // 32 KB each

  const int tid = threadIdx.x;
  const int wave = tid >> 6;  // 0..7
  const int lane = tid & 63;
  const int m0 = blockIdx.x * MT;
  const int lr = lane & 15;
  const int lq = lane >> 4;

  // A staging: tile = 256 chunks of 16B = 4 wave-instrs; waves 0..3 get one each.
  // instr i covers LDS chunks p = 64i+l: r = p>>3, c8 = (l&7)^(r&7).
  const bool hasA = wave < 4;
  const unsigned short* ag;
  int aoffu;
  {
    int i = hasA ? wave : 0;
    int p = 64 * i + lane;
    int r = p >> 3;
    int c8 = (lane & 7) ^ (r & 7);
    ag = adjb + (size_t)(m0 + r) * N_NODES + c8 * 8;
    aoffu = 1024 * i;
  }
  // B staging: 32 instrs, 4 per wave; wave w stages exactly its n-slice [32w,32w+32).
  const unsigned short* bg[4];
  int boffu[4];
#pragma unroll
  for (int q = 0; q < 4; ++q) {
    int i = wave * 4 + q;
    int p = 64 * i + lane;
    int n = p >> 3;
    int c8 = (lane & 7) ^ (n & 7);
    bg[q] = yt + (size_t)n * N_NODES + c8 * 8;
    boffu[q] = 1024 * i;
  }

  f32x4 acc[2][2];
#pragma unroll
  for (int i = 0; i < 2; ++i)
#pragma unroll
    for (int j = 0; j < 2; ++j) acc[i][j] = (f32x4){0.f, 0.f, 0.f, 0.f};

  auto issue = [&](int b, int k0) {
    char* aL = (char*)&As[b][0];
    char* bL = (char*)&Bs[b][0];
    if (hasA) async_copy16(ag + k0, aL + aoffu);
#pragma unroll
    for (int q = 0; q < 4; ++q) async_copy16(bg[q] + k0, bL + boffu[q]);
  };

  issue(0, 0);

  for (int kb = 0; kb < KB_COUNT; ++kb) {
    const int b = kb & 1;
    // vmcnt(0)+lgkmcnt(0)+barrier: tile b ready for all waves; buffer b^1 free.
    __syncthreads();
    if (kb + 1 < KB_COUNT) issue(b ^ 1, (kb + 1) * BK);

    const char* aB = (const char*)&As[b][0];
    const char* bB = (const char*)&Bs[b][0];

#pragma unroll
    for (int k32 = 0; k32 < 2; ++k32) {
      bf16x8 afr[2];
#pragma unroll
      for (int mt = 0; mt < 2; ++mt) {
        int row = mt * 16 + lr;
        int c8 = k32 * 4 + lq;
        int p = row * 8 + (c8 ^ (row & 7));
        afr[mt] = *(const bf16x8*)(aB + p * 16);
      }
#pragma unroll
      for (int nt = 0; nt < 2; ++nt) {
        int n = wave * 32 + nt * 16 + lr;
        int c8 = k32 * 4 + lq;
        int p = n * 8 + (c8 ^ (n & 7));
        bf16x8 bfr = *(const bf16x8*)(bB + p * 16);
        acc[0][nt] = __builtin_amdgcn_mfma_f32_16x16x32_bf16(afr[0], bfr, acc[0][nt], 0, 0, 0);
        acc[1][nt] = __builtin_amdgcn_mfma_f32_16x16x32_bf16(afr[1], bfr, acc[1][nt], 0, 0, 0);
      }
    }
  }

  // epilogue: out[i][c] = elu(dsq_i * (acc + dsq_i * z[i][c]))
#pragma unroll
  for (int mt = 0; mt < 2; ++mt) {
#pragma unroll
    for (int r = 0; r < 4; ++r) {
      int row = m0 + mt * 16 + lq * 4 + r;
      float di = dsq[row];
#pragma unroll
      for (int nt = 0; nt < 2; ++nt) {
        int col = wave * 32 + nt * 16 + lr;
        float v = acc[mt][nt][r];
        v = di * (v + di * z[(size_t)row * CH + col]);
        v = v > 0.f ? v : expm1f(v);
        out[(size_t)row * CH + col] = v;
      }
    }
  }
}

extern "C" void kernel_launch(void* const* d_in, const int* in_sizes, int n_in,
                              void* d_out, int out_size, void* d_ws, size_t ws_size,
                              hipStream_t stream) {
  const float* x = (const float*)d_in[0];
  const float* adj = (const float*)d_in[1];
  const float* w = (const float*)d_in[2];
  float* out = (float*)d_out;

  // ws layout: dsq @0 (32KB slot) ; yt @32768 (4MB) ; z @4227072 (8MB) ;
  //            adjb @12615680 (134MB)
  float* dsq = (float*)d_ws;
  unsigned short* yt = (unsigned short*)((char*)d_ws + 32768);
  float* z = (float*)((char*)d_ws + 4227072);
  unsigned short* adjb = (unsigned short*)((char*)d_ws + 12615680);

  k_pass1<<<ZBLOCKS + DEGBLOCKS, 256, 0, stream>>>(x, w, adj, z, dsq, adjb);
  k_y<<<N_NODES / 16, 256, 0, stream>>>(z, dsq, yt);
  k_gemm1<<<N_NODES / MT, 512, 0, stream>>>(adjb, yt, z, dsq, out);
}